// Round 6
// baseline (261.998 us; speedup 1.0000x reference)
//
#include <hip/hip_runtime.h>

// Problem constants: B=4, GX=480, GY=360, C_IN=64, C_OUT=32, N=480000
#define GXGY  172800        // GX*GY (multiple of 64: blocks never straddle batch)
#define NSEG  691200        // B*GX*GY
#define CIN   64
#define COUT  32
#define VPB   64            // voxels per block
#define PSTR  68            // pooled LDS stride (words): rows 16B-aligned for b128;
                            // phase-2 b128 bank pattern (4*lv+4j)%32 -> 2-way = free

// ---------------------------------------------------------------------------
// Pass A: per-voxel linked lists. head[seg]=-1 init; next[i] = old head.
// ---------------------------------------------------------------------------
__global__ __launch_bounds__(256) void build_lists_kernel(
    const int* __restrict__ ind,   // [N, 2]
    const int* __restrict__ bidx,  // [N]
    int*       __restrict__ head,  // [NSEG]
    int*       __restrict__ next,  // [N]
    int N)
{
    int i = blockIdx.x * 256 + threadIdx.x;
    if (i >= N) return;
    int2 xy = ((const int2*)ind)[i];
    int seg = bidx[i] * GXGY + xy.x * 360 + xy.y;
    next[i] = atomicExch(&head[seg], i);
}

// ---------------------------------------------------------------------------
// Pass B (fused pool+compress). Block = 256 threads = 64 voxels.
//
// R6 change: the CU-shared DS pipe was the tallest pole (~33 us/CU at b32
// granularity). All LDS traffic is now b128:
//   - phase 1: one ds_write_b128 per (chain, lane) instead of 4x b32
//   - phase 2: 16x ds_read_b128 per thread instead of 64x b32
//   PSTR=68 keeps rows 16B-aligned; both access patterns are 2 lanes/bank
//   per quarter-wave = conflict-free (m136: 2-way is free).
//
// Phase 1: each 16-lane subgroup walks its 4 chains concurrently.
//   fea row = 16 lanes x float4 = 256B coalesced per subgroup (1KB/wave-instr).
// Phase 2: thread (lv=tid&63, g=tid>>6) -> channels g*8..g*8+7 of voxel lv.
//   W/bias via readfirstlane-forced uniform loads -> SMEM broadcast (zero
//   LDS-pipe cost). Stores y-coalesced per channel.
// ---------------------------------------------------------------------------
__global__ __launch_bounds__(256) void pool_compress_kernel(
    const float* __restrict__ fea,   // [N, 64]
    const int*   __restrict__ head,  // [NSEG]
    const int*   __restrict__ next,  // [N]
    const float* __restrict__ W,     // [64, 32] row-major
    const float* __restrict__ bias,  // [32]
    float*       __restrict__ out)   // [B, 32, GX, GY]
{
    __shared__ float sP[VPB * PSTR];   // 17.0 KB pooled rows
    __shared__ int   sOcc[VPB];

    int tid  = threadIdx.x;
    int wid  = tid >> 6;
    int lane = tid & 63;
    int sub  = lane >> 4;    // subgroup 0..3
    int sl   = lane & 15;    // lane within subgroup

    int vbase = blockIdx.x * VPB;

    // This wave's 16 head pointers in one coalesced load, then distribute.
    int heads = (lane < 16) ? head[vbase + wid * 16 + lane] : -1;

    int idx[4];
    #pragma unroll
    for (int q = 0; q < 4; ++q) idx[q] = __shfl(heads, q * 4 + sub);

    unsigned occm = 0;
    #pragma unroll
    for (int q = 0; q < 4; ++q) if (idx[q] >= 0) occm |= (1u << q);

    if (sl == 0) {
        #pragma unroll
        for (int q = 0; q < 4; ++q)
            sOcc[wid * 16 + q * 4 + sub] = (occm >> q) & 1u;
    }

    // ---- Phase 1: 16 chains per wave, all concurrent ----
    float4 m[4];
    #pragma unroll
    for (int q = 0; q < 4; ++q) {
        if (idx[q] >= 0) {
            m[q] = *((const float4*)(fea + (size_t)idx[q] * CIN) + sl);
            idx[q] = next[idx[q]];
        }
    }
    while (idx[0] >= 0 || idx[1] >= 0 || idx[2] >= 0 || idx[3] >= 0) {
        #pragma unroll
        for (int q = 0; q < 4; ++q) {
            if (idx[q] >= 0) {
                float4 t = *((const float4*)(fea + (size_t)idx[q] * CIN) + sl);
                m[q].x = fmaxf(m[q].x, t.x);
                m[q].y = fmaxf(m[q].y, t.y);
                m[q].z = fmaxf(m[q].z, t.z);
                m[q].w = fmaxf(m[q].w, t.w);
                idx[q] = next[idx[q]];
            }
        }
    }
    #pragma unroll
    for (int q = 0; q < 4; ++q) {
        if (occm & (1u << q)) {
            int lv = wid * 16 + q * 4 + sub;
            *((float4*)&sP[lv * PSTR + sl * 4]) = m[q];   // ds_write_b128
        }
    }
    __syncthreads();

    // ---- Phase 2: 64x8 matvec per thread, W from SMEM, pooled via b128 ----
    int lv = lane;                                   // voxel within block
    int g  = __builtin_amdgcn_readfirstlane(wid);    // wave-uniform SGPR
    int b  = vbase / GXGY;                           // uniform per block
    int rem = vbase - b * GXGY + lv;

    const float* Wg = W + g * 8;                     // uniform base -> s_load
    const float* bg = bias + g * 8;

    float res[8];
    if (sOcc[lv]) {
        float acc[8];
        #pragma unroll
        for (int c = 0; c < 8; ++c) acc[c] = bg[c];
        #pragma unroll
        for (int kq = 0; kq < CIN / 4; ++kq) {
            float4 p = *((const float4*)&sP[lv * PSTR + kq * 4]);  // ds_read_b128
            const float* w = Wg + (kq * 4) * COUT;
            #pragma unroll
            for (int c = 0; c < 8; ++c) {
                acc[c] = fmaf(p.x, w[0 * COUT + c], acc[c]);
                acc[c] = fmaf(p.y, w[1 * COUT + c], acc[c]);
                acc[c] = fmaf(p.z, w[2 * COUT + c], acc[c]);
                acc[c] = fmaf(p.w, w[3 * COUT + c], acc[c]);
            }
        }
        #pragma unroll
        for (int c = 0; c < 8; ++c) res[c] = fmaxf(acc[c], 0.0f);
    } else {
        #pragma unroll
        for (int c = 0; c < 8; ++c) res[c] = 0.0f;
    }

    float* op = out + (size_t)b * COUT * GXGY + (size_t)g * 8 * GXGY + rem;
    #pragma unroll
    for (int c = 0; c < 8; ++c) op[c * GXGY] = res[c];
}

extern "C" void kernel_launch(void* const* d_in, const int* in_sizes, int n_in,
                              void* d_out, int out_size, void* d_ws, size_t ws_size,
                              hipStream_t stream)
{
    const float* fea  = (const float*)d_in[0];
    const int*   ind  = (const int*)d_in[1];
    const int*   bidx = (const int*)d_in[2];
    const float* W    = (const float*)d_in[3];
    const float* bias = (const float*)d_in[4];
    float*       out  = (float*)d_out;

    int N = in_sizes[0] / CIN;  // 480000

    int* head = (int*)d_ws;           // NSEG ints (2.76 MB)
    int* next = (int*)d_ws + NSEG;    // N ints (1.92 MB)

    hipMemsetAsync(head, 0xFF, (size_t)NSEG * sizeof(int), stream);
    build_lists_kernel<<<(N + 255) / 256, 256, 0, stream>>>(ind, bidx, head, next, N);
    pool_compress_kernel<<<NSEG / VPB, 256, 0, stream>>>(fea, head, next, W, bias, out);
}